// Round 8
// baseline (575.608 us; speedup 1.0000x reference)
//
#include <hip/hip_runtime.h>

#define D_MODEL 1024
#define S_LEN   2048
#define BATCH   4
#define NH      16
#define DH      64
#define M_ROWS  (BATCH * S_LEN)   // 8192

typedef __attribute__((ext_vector_type(8))) short short8;
typedef __attribute__((ext_vector_type(4))) float floatx4;
typedef unsigned short ushort_t;
typedef __attribute__((ext_vector_type(4))) ushort_t ushortx4;

__device__ __forceinline__ ushort_t f2bf(float f) {
    union { float f; unsigned u; } v; v.f = f;
    unsigned r = v.u + 0x7FFFu + ((v.u >> 16) & 1u);
    return (ushort_t)(r >> 16);
}

// pack two f32 -> two bf16 (truncating) in one v_perm: low = lo, high = hi
__device__ __forceinline__ int pack2(float lo, float hi) {
    return (int)__builtin_amdgcn_perm(__float_as_uint(hi), __float_as_uint(lo), 0x07060302u);
}

// max over the 16 lanes of a DPP row via row_ror — no LDS round-trip
__device__ __forceinline__ float rowmax16(float x) {
    float t;
    t = __int_as_float(__builtin_amdgcn_update_dpp(0, __float_as_int(x), 0x121, 0xf, 0xf, true)); x = fmaxf(x, t);
    t = __int_as_float(__builtin_amdgcn_update_dpp(0, __float_as_int(x), 0x122, 0xf, 0xf, true)); x = fmaxf(x, t);
    t = __int_as_float(__builtin_amdgcn_update_dpp(0, __float_as_int(x), 0x124, 0xf, 0xf, true)); x = fmaxf(x, t);
    t = __int_as_float(__builtin_amdgcn_update_dpp(0, __float_as_int(x), 0x128, 0xf, 0xf, true)); x = fmaxf(x, t);
    return x;
}

// async global->LDS, 16B/lane; LDS dest = wave-uniform base + lane*16
__device__ __forceinline__ void async_copy16(const ushort_t* g, ushort_t* l) {
    __builtin_amdgcn_global_load_lds(
        (const __attribute__((address_space(1))) void*)g,
        (__attribute__((address_space(3))) void*)l,
        16, 0, 0);
}

// ---------------------------------------------------------------------------
// fp32 -> bf16 downcast of x, W_qkv, W_o into workspace. 4 elems / thread.
// ---------------------------------------------------------------------------
#define N0 (M_ROWS * D_MODEL)        // x:      8,388,608
#define N1 (3 * D_MODEL * D_MODEL)   // W_qkv:  3,145,728
#define N2 (D_MODEL * D_MODEL)       // W_o:    1,048,576
#define NQUADS ((N0 + N1 + N2) / 4)

__global__ __launch_bounds__(256)
void cvt_f32_bf16(const float* __restrict__ s0, const float* __restrict__ s1,
                  const float* __restrict__ s2, ushort_t* __restrict__ d0,
                  ushort_t* __restrict__ d1, ushort_t* __restrict__ d2)
{
    const int q = blockIdx.x * 256 + threadIdx.x;
    if (q >= NQUADS) return;
    const float* s; ushort_t* d; int e;
    if (q < N0 / 4)            { s = s0; d = d0; e = q * 4; }
    else if (q < (N0 + N1) / 4){ s = s1; d = d1; e = q * 4 - N0; }
    else                       { s = s2; d = d2; e = q * 4 - N0 - N1; }
    const float4 v = *(const float4*)&s[e];
    ushortx4 o;
    o[0] = f2bf(v.x); o[1] = f2bf(v.y); o[2] = f2bf(v.z); o[3] = f2bf(v.w);
    *(ushortx4*)&d[e] = o;
}

// ---------------------------------------------------------------------------
// NT GEMM: C[M,N] = A[M,K] * B[N,K]^T + bias[N]. bf16 in, fp32 acc.
// BK=64, DMA staging (global_load_lds w16), XOR-swizzled unpadded LDS tiles
// (col8 ^= row&7) -> conflict-free b128 fragment reads.
// VSPLIT (QKV): cols [0,2048) -> qk; cols [2048,3072) -> vt[b][h][dh][sperm]
// where sperm applies pos(k)=(k&15)*4+(k>>4) within each 64-key tile (matches
// the attention kernel's P/V fragment ordering).
// ---------------------------------------------------------------------------
template<bool F32OUT, bool VSPLIT>
__global__ __launch_bounds__(256)
void gemm_bt_bias(const ushort_t* __restrict__ A, const ushort_t* __restrict__ B,
                  const float* __restrict__ bias, void* __restrict__ Cv,
                  ushort_t* __restrict__ vt, int M, int N, int K)
{
    constexpr int BK = 64;
    __shared__ ushort_t As[128][BK];   // 128B rows, lane-linear for DMA
    __shared__ ushort_t Bs[128][BK];

    const int tid  = threadIdx.x;
    const int lane = tid & 63;
    const int wave = tid >> 6;
    const int quad = lane >> 4;
    const int l16  = lane & 15;
    const int bm   = blockIdx.y * 128;
    const int bn   = blockIdx.x * 128;
    const int wm   = (wave & 1) * 64;
    const int wn   = (wave >> 1) * 64;

    floatx4 acc[4][4] = {};

    // DMA map: 8 rows/instr; lane -> row l>>3, col8p = l&7, src col8 = col8p^row&7
    const int l8r = lane >> 3;
    const int c8  = lane & 7;
    const int swz = l16 & 7;          // fragment-read swizzle bits

    for (int k0 = 0; k0 < K; k0 += BK) {
        __syncthreads();
        #pragma unroll
        for (int i = wave; i < 16; i += 4) {
            const int row = i * 8 + l8r;
            const int cc  = (c8 ^ l8r) * 8;
            async_copy16(&A[(size_t)(bm + row) * K + k0 + cc], &As[i * 8][0]);
            async_copy16(&B[(size_t)(bn + row) * K + k0 + cc], &Bs[i * 8][0]);
        }
        __syncthreads();

        #pragma unroll
        for (int h = 0; h < 2; h++) {
            short8 af[4], bfr[4];
            #pragma unroll
            for (int i = 0; i < 4; i++)
                af[i]  = *(const short8*)&As[wm + i * 16 + l16][((h * 4 + quad) ^ swz) * 8];
            #pragma unroll
            for (int i = 0; i < 4; i++)
                bfr[i] = *(const short8*)&Bs[wn + i * 16 + l16][((h * 4 + quad) ^ swz) * 8];

            #pragma unroll
            for (int mi = 0; mi < 4; mi++)
                #pragma unroll
                for (int ni = 0; ni < 4; ni++)
                    acc[mi][ni] = __builtin_amdgcn_mfma_f32_16x16x32_bf16(af[mi], bfr[ni], acc[mi][ni], 0, 0, 0);
        }
    }

    // Epilogue: C/D layout col = lane&15, row = quad*4 + reg
    #pragma unroll
    for (int ni = 0; ni < 4; ni++) {
        const int col = bn + wn + ni * 16 + l16;
        const float bv = bias[col];
        #pragma unroll
        for (int mi = 0; mi < 4; mi++)
            #pragma unroll
            for (int r = 0; r < 4; r++) {
                const int row = bm + wm + mi * 16 + quad * 4 + r;
                const float val = acc[mi][ni][r] + bv;
                if (VSPLIT) {
                    if (col < 2 * D_MODEL) {   // block-uniform branch
                        ((ushort_t*)Cv)[(size_t)row * 2048 + col] = f2bf(val);
                    } else {
                        const int vcol = col - 2 * D_MODEL;
                        const int h = vcol >> 6, dh = vcol & 63;
                        const int b = row >> 11, s = row & 2047;
                        const int sp = (s & ~63) | ((s & 15) << 2) | ((s >> 4) & 3);
                        vt[(((size_t)(b * NH + h)) * DH + dh) * S_LEN + sp] = f2bf(val);
                    }
                } else if (F32OUT) {
                    ((float*)Cv)[(size_t)row * N + col] = val;
                } else {
                    ((ushort_t*)Cv)[(size_t)row * N + col] = f2bf(val);
                }
            }
    }
}

// ---------------------------------------------------------------------------
// Causal flash attention. qk: [B,S,2048] (Q|K packed bf16).
// vt: [B,H,DH,S] V^T with per-64-tile position permutation pos(k)=(k&15)*4+(k>>4).
// Block = one (b,h) x 128 q rows; 4 waves x 32 rows (2 m-frags); BKV=64.
// K/V staged via global_load_lds into XOR-swizzled unpadded [64][64] tiles
// (conflict-free b128 reads, no scalar scatter). LDS 25 KB -> 5 blocks/CU.
// Softmax exp2-domain, DPP row-max, P packed via v_perm, row sums via MFMA.
// ---------------------------------------------------------------------------
#define BQ  128
#define BKV 64

__global__ __launch_bounds__(256, 5)
void attn_causal(const ushort_t* __restrict__ qk, const ushort_t* __restrict__ vt,
                 ushort_t* __restrict__ out)
{
    __shared__ ushort_t Ks[BKV][DH];          // [key][dh]  swizzled   (8 KB)
    __shared__ ushort_t Vs[DH][BKV];          // [dh][pos]  swizzled   (8 KB)
    __shared__ ushort_t Ps[4][16][BKV + 4];   // per-wave [row][pos]   (8.5 KB)

    const int tid  = threadIdx.x;
    const int lane = tid & 63;
    const int wave = tid >> 6;
    const int quad = lane >> 4;
    const int l16  = lane & 15;
    const int l8r  = lane >> 3;
    const int c8   = lane & 7;
    const int swz  = l16 & 7;

    const int qt = (int)gridDim.x - 1 - (int)blockIdx.x;   // heavy blocks first
    const int bh = blockIdx.y;
    const int b  = bh >> 4;
    const int h  = bh & 15;
    const int q0 = qt * BQ;

    const float C2 = 0.18033688011112042f;   // 0.125 * log2(e)

    const size_t qkbase = (size_t)b * S_LEN * 2048;

    // Q A-fragments straight from global: A[m=l16][k=quad*8+j]
    short8 qf[2][2];
    #pragma unroll
    for (int mi = 0; mi < 2; mi++) {
        const ushort_t* qp = qk + qkbase + (size_t)(q0 + wave * 32 + mi * 16 + l16) * 2048 + h * DH;
        qf[mi][0] = *(const short8*)(qp + quad * 8);
        qf[mi][1] = *(const short8*)(qp + 32 + quad * 8);
    }

    const ushort_t* kg = qk + qkbase + D_MODEL + h * DH;            // + key*2048
    const ushort_t* vg = vt + (size_t)(b * NH + h) * DH * S_LEN;    // + dh*S + pos

    float m_run[2][4], l_run[2][4];
    floatx4 o_acc[2][4] = {};
    #pragma unroll
    for (int mi = 0; mi < 2; mi++)
        #pragma unroll
        for (int r = 0; r < 4; r++) { m_run[mi][r] = -1e30f; l_run[mi][r] = 0.f; }

    short8 ones;
    #pragma unroll
    for (int j = 0; j < 8; j++) ones[j] = (short)0x3F80;   // bf16 1.0

    const int ntiles = 2 * qt + 2;
    for (int t = 0; t < ntiles; t++) {
        const int kb = t * BKV;
        __syncthreads();
        #pragma unroll
        for (int i = wave; i < 8; i += 4) {
            const int row = i * 8 + l8r;
            const int cc  = (c8 ^ l8r) * 8;
            async_copy16(&kg[(size_t)(kb + row) * 2048 + cc], &Ks[i * 8][0]);
            async_copy16(&vg[(size_t)row * S_LEN + kb + cc], &Vs[i * 8][0]);
        }
        __syncthreads();

        const int shift = kb - q0;                 // >0 only on the top diag tile
        if (shift > wave * 32 + 31) continue;      // wave fully masked (barriers done)
        const bool nmask = (wave * 32 < shift + 63);

        #pragma unroll
        for (int mi = 0; mi < 2; mi++) {
            // ---- S = Q K^T (swizzled K reads, conflict-free)
            floatx4 sc[4];
            #pragma unroll
            for (int ns = 0; ns < 4; ns++) {
                const short8 kf0 = *(const short8*)&Ks[ns * 16 + l16][(quad ^ swz) * 8];
                const short8 kf1 = *(const short8*)&Ks[ns * 16 + l16][((4 + quad) ^ swz) * 8];
                floatx4 z = {};
                z = __builtin_amdgcn_mfma_f32_16x16x32_bf16(qf[mi][0], kf0, z, 0, 0, 0);
                z = __builtin_amdgcn_mfma_f32_16x16x32_bf16(qf[mi][1], kf1, z, 0, 0, 0);
                sc[ns] = z;
            }

            // ---- exp2-domain scale + causal mask + DPP row max
            float mt[4];
            #pragma unroll
            for (int r = 0; r < 4; r++) {
                const int qloc = wave * 32 + mi * 16 + quad * 4 + r;
                float mx = -1e30f;
                #pragma unroll
                for (int ns = 0; ns < 4; ns++) {
                    float v = sc[ns][r] * C2;
                    if (nmask) {
                        const int kj = ns * 16 + l16;
                        v = (kj <= qloc - shift) ? v : -1e30f;
                    }
                    sc[ns][r] = v;
                    mx = fmaxf(mx, v);
                }
                mt[r] = rowmax16(mx);
            }

            // ---- online update + exp2 + pack + one b64 write per row
            float alpha[4];
            #pragma unroll
            for (int r = 0; r < 4; r++) {
                const float mnew = fmaxf(m_run[mi][r], mt[r]);
                alpha[r] = __builtin_amdgcn_exp2f(m_run[mi][r] - mnew);
                m_run[mi][r] = mnew;
                const float p0 = __builtin_amdgcn_exp2f(sc[0][r] - mnew);
                const float p1 = __builtin_amdgcn_exp2f(sc[1][r] - mnew);
                const float p2 = __builtin_amdgcn_exp2f(sc[2][r] - mnew);
                const float p3 = __builtin_amdgcn_exp2f(sc[3][r] - mnew);
                int2 w;
                w.x = pack2(p0, p1);
                w.y = pack2(p2, p3);
                *(int2*)&Ps[wave][quad * 4 + r][l16 * 4] = w;
            }

            // ---- P A-fragments (same-wave RAW through LDS)
            short8 pf[2];
            #pragma unroll
            for (int c = 0; c < 2; c++)
                pf[c] = *(const short8*)&Ps[wave][l16][c * 32 + quad * 8];

            // ---- row sums via MFMA
            floatx4 racc = {};
            racc = __builtin_amdgcn_mfma_f32_16x16x32_bf16(pf[0], ones, racc, 0, 0, 0);
            racc = __builtin_amdgcn_mfma_f32_16x16x32_bf16(pf[1], ones, racc, 0, 0, 0);

            #pragma unroll
            for (int r = 0; r < 4; r++)
                l_run[mi][r] = l_run[mi][r] * alpha[r] + racc[r];

            #pragma unroll
            for (int d = 0; d < 4; d++)
                #pragma unroll
                for (int r = 0; r < 4; r++)
                    o_acc[mi][d][r] *= alpha[r];

            // ---- O += P V (swizzled V reads; position-permuted both sides)
            #pragma unroll
            for (int d = 0; d < 4; d++) {
                #pragma unroll
                for (int c = 0; c < 2; c++) {
                    const short8 vf = *(const short8*)&Vs[d * 16 + l16][((c * 4 + quad) ^ swz) * 8];
                    o_acc[mi][d] = __builtin_amdgcn_mfma_f32_16x16x32_bf16(pf[c], vf, o_acc[mi][d], 0, 0, 0);
                }
            }
        }
    }

    // ---- out[b, qi, h*64 + dh] = o / l
    #pragma unroll
    for (int mi = 0; mi < 2; mi++)
        #pragma unroll
        for (int r = 0; r < 4; r++) {
            const float inv = 1.0f / l_run[mi][r];
            const int qi = q0 + wave * 32 + mi * 16 + quad * 4 + r;
            #pragma unroll
            for (int d = 0; d < 4; d++)
                out[(size_t)(b * S_LEN + qi) * D_MODEL + h * DH + d * 16 + l16] =
                    f2bf(o_acc[mi][d][r] * inv);
        }
}

// ---------------------------------------------------------------------------
extern "C" void kernel_launch(void* const* d_in, const int* in_sizes, int n_in,
                              void* d_out, int out_size, void* d_ws, size_t ws_size,
                              hipStream_t stream)
{
    const float* x    = (const float*)d_in[0];
    const float* Wqkv = (const float*)d_in[1];
    const float* bqkv = (const float*)d_in[2];
    const float* Wo   = (const float*)d_in[3];
    const float* bo   = (const float*)d_in[4];
    float* out = (float*)d_out;

    ushort_t* xb    = (ushort_t*)d_ws;                       // N0
    ushort_t* wqkvb = xb + N0;                               // N1
    ushort_t* wob   = wqkvb + N1;                            // N2
    ushort_t* qkbuf = wob + N2;                              // 8192*2048
    ushort_t* vtbuf = qkbuf + (size_t)M_ROWS * 2048;         // B*NH*DH*S
    ushort_t* att   = vtbuf + (size_t)BATCH * NH * DH * S_LEN; // 8192*1024
    // total = 92.3 MB

    dim3 blk(256);
    cvt_f32_bf16<<<dim3((NQUADS + 255) / 256), blk, 0, stream>>>(x, Wqkv, Wo, xb, wqkvb, wob);
    // QKV projection: M=8192, N=3072, K=1024 -> qk (packed Q|K) + vt (V^T, permuted)
    gemm_bt_bias<false, true><<<dim3((3 * D_MODEL) / 128, M_ROWS / 128), blk, 0, stream>>>(
        xb, wqkvb, bqkv, qkbuf, vtbuf, M_ROWS, 3 * D_MODEL, D_MODEL);
    // causal attention
    attn_causal<<<dim3(S_LEN / BQ, BATCH * NH), blk, 0, stream>>>(qkbuf, vtbuf, att);
    // output projection: M=8192, N=1024, K=1024 -> fp32 d_out
    gemm_bt_bias<true, false><<<dim3(D_MODEL / 128, M_ROWS / 128), blk, 0, stream>>>(
        att, wob, bo, out, nullptr, M_ROWS, D_MODEL, D_MODEL);
}

// Round 9
// 343.191 us; speedup vs baseline: 1.6772x; 1.6772x over previous
//
#include <hip/hip_runtime.h>

#define D_MODEL 1024
#define S_LEN   2048
#define BATCH   4
#define NH      16
#define DH      64
#define M_ROWS  (BATCH * S_LEN)   // 8192

typedef __attribute__((ext_vector_type(8))) short short8;
typedef __attribute__((ext_vector_type(4))) float floatx4;
typedef unsigned short ushort_t;
typedef __attribute__((ext_vector_type(4))) ushort_t ushortx4;

__device__ __forceinline__ ushort_t f2bf(float f) {
    union { float f; unsigned u; } v; v.f = f;
    unsigned r = v.u + 0x7FFFu + ((v.u >> 16) & 1u);
    return (ushort_t)(r >> 16);
}

// pack two f32 -> two bf16 (truncating) in one v_perm: low = lo, high = hi
__device__ __forceinline__ int pack2(float lo, float hi) {
    return (int)__builtin_amdgcn_perm(__float_as_uint(hi), __float_as_uint(lo), 0x07060302u);
}

// max over the 16 lanes of a DPP row via row_ror — no LDS round-trip
__device__ __forceinline__ float rowmax16(float x) {
    float t;
    t = __int_as_float(__builtin_amdgcn_update_dpp(0, __float_as_int(x), 0x121, 0xf, 0xf, true)); x = fmaxf(x, t);
    t = __int_as_float(__builtin_amdgcn_update_dpp(0, __float_as_int(x), 0x122, 0xf, 0xf, true)); x = fmaxf(x, t);
    t = __int_as_float(__builtin_amdgcn_update_dpp(0, __float_as_int(x), 0x124, 0xf, 0xf, true)); x = fmaxf(x, t);
    t = __int_as_float(__builtin_amdgcn_update_dpp(0, __float_as_int(x), 0x128, 0xf, 0xf, true)); x = fmaxf(x, t);
    return x;
}

// async global->LDS, 16B/lane; LDS dest = wave-uniform base + lane*16
__device__ __forceinline__ void async_copy16(const ushort_t* g, ushort_t* l) {
    __builtin_amdgcn_global_load_lds(
        (const __attribute__((address_space(1))) void*)g,
        (__attribute__((address_space(3))) void*)l,
        16, 0, 0);
}

// ---------------------------------------------------------------------------
// fp32 -> bf16 downcast of x, W_qkv, W_o into workspace. 4 elems / thread.
// ---------------------------------------------------------------------------
#define N0 (M_ROWS * D_MODEL)        // x:      8,388,608
#define N1 (3 * D_MODEL * D_MODEL)   // W_qkv:  3,145,728
#define N2 (D_MODEL * D_MODEL)       // W_o:    1,048,576
#define NQUADS ((N0 + N1 + N2) / 4)

__global__ __launch_bounds__(256)
void cvt_f32_bf16(const float* __restrict__ s0, const float* __restrict__ s1,
                  const float* __restrict__ s2, ushort_t* __restrict__ d0,
                  ushort_t* __restrict__ d1, ushort_t* __restrict__ d2)
{
    const int q = blockIdx.x * 256 + threadIdx.x;
    if (q >= NQUADS) return;
    const float* s; ushort_t* d; int e;
    if (q < N0 / 4)            { s = s0; d = d0; e = q * 4; }
    else if (q < (N0 + N1) / 4){ s = s1; d = d1; e = q * 4 - N0; }
    else                       { s = s2; d = d2; e = q * 4 - N0 - N1; }
    const float4 v = *(const float4*)&s[e];
    ushortx4 o;
    o[0] = f2bf(v.x); o[1] = f2bf(v.y); o[2] = f2bf(v.z); o[3] = f2bf(v.w);
    *(ushortx4*)&d[e] = o;
}

// ---------------------------------------------------------------------------
// NT GEMM: C[M,N] = A[M,K] * B[N,K]^T + bias[N]. bf16 in, fp32 acc.
// BK=64, DMA staging (global_load_lds w16), XOR-swizzled unpadded LDS tiles
// (col8 ^= row&7) -> conflict-free b128 fragment reads.
// VSPLIT (QKV): cols [0,2048) -> qk; cols [2048,3072) -> vt[b][h][dh][sperm]
// where sperm applies pos(k)=(k&15)*4+(k>>4) within each 64-key tile (matches
// the attention kernel's P/V fragment ordering).
// ---------------------------------------------------------------------------
template<bool F32OUT, bool VSPLIT>
__global__ __launch_bounds__(256)
void gemm_bt_bias(const ushort_t* __restrict__ A, const ushort_t* __restrict__ B,
                  const float* __restrict__ bias, void* __restrict__ Cv,
                  ushort_t* __restrict__ vt, int M, int N, int K)
{
    constexpr int BK = 64;
    __shared__ ushort_t As[128][BK];   // 128B rows, lane-linear for DMA
    __shared__ ushort_t Bs[128][BK];

    const int tid  = threadIdx.x;
    const int lane = tid & 63;
    const int wave = tid >> 6;
    const int quad = lane >> 4;
    const int l16  = lane & 15;
    const int bm   = blockIdx.y * 128;
    const int bn   = blockIdx.x * 128;
    const int wm   = (wave & 1) * 64;
    const int wn   = (wave >> 1) * 64;

    floatx4 acc[4][4] = {};

    // DMA map: 8 rows/instr; lane -> row l>>3, col8p = l&7, src col8 = col8p^row&7
    const int l8r = lane >> 3;
    const int c8  = lane & 7;
    const int swz = l16 & 7;          // fragment-read swizzle bits

    for (int k0 = 0; k0 < K; k0 += BK) {
        __syncthreads();
        #pragma unroll
        for (int i = wave; i < 16; i += 4) {
            const int row = i * 8 + l8r;
            const int cc  = (c8 ^ l8r) * 8;
            async_copy16(&A[(size_t)(bm + row) * K + k0 + cc], &As[i * 8][0]);
            async_copy16(&B[(size_t)(bn + row) * K + k0 + cc], &Bs[i * 8][0]);
        }
        __syncthreads();

        #pragma unroll
        for (int h = 0; h < 2; h++) {
            short8 af[4], bfr[4];
            #pragma unroll
            for (int i = 0; i < 4; i++)
                af[i]  = *(const short8*)&As[wm + i * 16 + l16][((h * 4 + quad) ^ swz) * 8];
            #pragma unroll
            for (int i = 0; i < 4; i++)
                bfr[i] = *(const short8*)&Bs[wn + i * 16 + l16][((h * 4 + quad) ^ swz) * 8];

            #pragma unroll
            for (int mi = 0; mi < 4; mi++)
                #pragma unroll
                for (int ni = 0; ni < 4; ni++)
                    acc[mi][ni] = __builtin_amdgcn_mfma_f32_16x16x32_bf16(af[mi], bfr[ni], acc[mi][ni], 0, 0, 0);
        }
    }

    // Epilogue: C/D layout col = lane&15, row = quad*4 + reg
    #pragma unroll
    for (int ni = 0; ni < 4; ni++) {
        const int col = bn + wn + ni * 16 + l16;
        const float bv = bias[col];
        #pragma unroll
        for (int mi = 0; mi < 4; mi++)
            #pragma unroll
            for (int r = 0; r < 4; r++) {
                const int row = bm + wm + mi * 16 + quad * 4 + r;
                const float val = acc[mi][ni][r] + bv;
                if (VSPLIT) {
                    if (col < 2 * D_MODEL) {   // block-uniform branch
                        ((ushort_t*)Cv)[(size_t)row * 2048 + col] = f2bf(val);
                    } else {
                        const int vcol = col - 2 * D_MODEL;
                        const int h = vcol >> 6, dh = vcol & 63;
                        const int b = row >> 11, s = row & 2047;
                        const int sp = (s & ~63) | ((s & 15) << 2) | ((s >> 4) & 3);
                        vt[(((size_t)(b * NH + h)) * DH + dh) * S_LEN + sp] = f2bf(val);
                    }
                } else if (F32OUT) {
                    ((float*)Cv)[(size_t)row * N + col] = val;
                } else {
                    ((ushort_t*)Cv)[(size_t)row * N + col] = f2bf(val);
                }
            }
    }
}

// ---------------------------------------------------------------------------
// Causal flash attention. qk: [B,S,2048] (Q|K packed bf16).
// vt: [B,H,DH,S] V^T with per-64-tile position permutation pos(k)=(k&15)*4+(k>>4).
// Block = one (b,h) x 128 q rows; 4 waves x 32 rows (2 m-frags); BKV=64.
// K/V staged via global_load_lds into XOR-swizzled unpadded [64][64] tiles
// (conflict-free b128 reads — R8 measured SQ_LDS_BANK_CONFLICT=0).
// LDS 25 KB; __launch_bounds__(256,4) = 128-VGPR cap: kernel needs ~90-100
// regs — fits with NO spills (R8's (256,5)=102-cap spilled ~450 MB/launch).
// Softmax exp2-domain, DPP row-max, P packed via v_perm, row sums via MFMA.
// ---------------------------------------------------------------------------
#define BQ  128
#define BKV 64

__global__ __launch_bounds__(256, 4)
void attn_causal(const ushort_t* __restrict__ qk, const ushort_t* __restrict__ vt,
                 ushort_t* __restrict__ out)
{
    __shared__ ushort_t Ks[BKV][DH];          // [key][dh]  swizzled   (8 KB)
    __shared__ ushort_t Vs[DH][BKV];          // [dh][pos]  swizzled   (8 KB)
    __shared__ ushort_t Ps[4][16][BKV + 4];   // per-wave [row][pos]   (8.5 KB)

    const int tid  = threadIdx.x;
    const int lane = tid & 63;
    const int wave = tid >> 6;
    const int quad = lane >> 4;
    const int l16  = lane & 15;
    const int l8r  = lane >> 3;
    const int c8   = lane & 7;
    const int swz  = l16 & 7;

    const int qt = (int)gridDim.x - 1 - (int)blockIdx.x;   // heavy blocks first
    const int bh = blockIdx.y;
    const int b  = bh >> 4;
    const int h  = bh & 15;
    const int q0 = qt * BQ;

    const float C2 = 0.18033688011112042f;   // 0.125 * log2(e)

    const size_t qkbase = (size_t)b * S_LEN * 2048;

    // Q A-fragments straight from global: A[m=l16][k=quad*8+j]
    short8 qf[2][2];
    #pragma unroll
    for (int mi = 0; mi < 2; mi++) {
        const ushort_t* qp = qk + qkbase + (size_t)(q0 + wave * 32 + mi * 16 + l16) * 2048 + h * DH;
        qf[mi][0] = *(const short8*)(qp + quad * 8);
        qf[mi][1] = *(const short8*)(qp + 32 + quad * 8);
    }

    const ushort_t* kg = qk + qkbase + D_MODEL + h * DH;            // + key*2048
    const ushort_t* vg = vt + (size_t)(b * NH + h) * DH * S_LEN;    // + dh*S + pos

    float m_run[2][4], l_run[2][4];
    floatx4 o_acc[2][4] = {};
    #pragma unroll
    for (int mi = 0; mi < 2; mi++)
        #pragma unroll
        for (int r = 0; r < 4; r++) { m_run[mi][r] = -1e30f; l_run[mi][r] = 0.f; }

    short8 ones;
    #pragma unroll
    for (int j = 0; j < 8; j++) ones[j] = (short)0x3F80;   // bf16 1.0

    const int ntiles = 2 * qt + 2;
    for (int t = 0; t < ntiles; t++) {
        const int kb = t * BKV;
        __syncthreads();
        #pragma unroll
        for (int i = wave; i < 8; i += 4) {
            const int row = i * 8 + l8r;
            const int cc  = (c8 ^ l8r) * 8;
            async_copy16(&kg[(size_t)(kb + row) * 2048 + cc], &Ks[i * 8][0]);
            async_copy16(&vg[(size_t)row * S_LEN + kb + cc], &Vs[i * 8][0]);
        }
        __syncthreads();

        const int shift = kb - q0;                 // >0 only on the top diag tile
        if (shift > wave * 32 + 31) continue;      // wave fully masked (barriers done)
        const bool nmask = (wave * 32 < shift + 63);

        #pragma unroll
        for (int mi = 0; mi < 2; mi++) {
            // ---- S = Q K^T (swizzled K reads, conflict-free)
            floatx4 sc[4];
            #pragma unroll
            for (int ns = 0; ns < 4; ns++) {
                const short8 kf0 = *(const short8*)&Ks[ns * 16 + l16][(quad ^ swz) * 8];
                const short8 kf1 = *(const short8*)&Ks[ns * 16 + l16][((4 + quad) ^ swz) * 8];
                floatx4 z = {};
                z = __builtin_amdgcn_mfma_f32_16x16x32_bf16(qf[mi][0], kf0, z, 0, 0, 0);
                z = __builtin_amdgcn_mfma_f32_16x16x32_bf16(qf[mi][1], kf1, z, 0, 0, 0);
                sc[ns] = z;
            }

            // ---- exp2-domain scale + causal mask + DPP row max
            float mt[4];
            #pragma unroll
            for (int r = 0; r < 4; r++) {
                const int qloc = wave * 32 + mi * 16 + quad * 4 + r;
                float mx = -1e30f;
                #pragma unroll
                for (int ns = 0; ns < 4; ns++) {
                    float v = sc[ns][r] * C2;
                    if (nmask) {
                        const int kj = ns * 16 + l16;
                        v = (kj <= qloc - shift) ? v : -1e30f;
                    }
                    sc[ns][r] = v;
                    mx = fmaxf(mx, v);
                }
                mt[r] = rowmax16(mx);
            }

            // ---- online update + exp2 + pack + one b64 write per row
            float alpha[4];
            #pragma unroll
            for (int r = 0; r < 4; r++) {
                const float mnew = fmaxf(m_run[mi][r], mt[r]);
                alpha[r] = __builtin_amdgcn_exp2f(m_run[mi][r] - mnew);
                m_run[mi][r] = mnew;
                const float p0 = __builtin_amdgcn_exp2f(sc[0][r] - mnew);
                const float p1 = __builtin_amdgcn_exp2f(sc[1][r] - mnew);
                const float p2 = __builtin_amdgcn_exp2f(sc[2][r] - mnew);
                const float p3 = __builtin_amdgcn_exp2f(sc[3][r] - mnew);
                int2 w;
                w.x = pack2(p0, p1);
                w.y = pack2(p2, p3);
                *(int2*)&Ps[wave][quad * 4 + r][l16 * 4] = w;
            }

            // ---- P A-fragments (same-wave RAW through LDS)
            short8 pf[2];
            #pragma unroll
            for (int c = 0; c < 2; c++)
                pf[c] = *(const short8*)&Ps[wave][l16][c * 32 + quad * 8];

            // ---- row sums via MFMA
            floatx4 racc = {};
            racc = __builtin_amdgcn_mfma_f32_16x16x32_bf16(pf[0], ones, racc, 0, 0, 0);
            racc = __builtin_amdgcn_mfma_f32_16x16x32_bf16(pf[1], ones, racc, 0, 0, 0);

            #pragma unroll
            for (int r = 0; r < 4; r++)
                l_run[mi][r] = l_run[mi][r] * alpha[r] + racc[r];

            #pragma unroll
            for (int d = 0; d < 4; d++)
                #pragma unroll
                for (int r = 0; r < 4; r++)
                    o_acc[mi][d][r] *= alpha[r];

            // ---- O += P V (swizzled V reads; position-permuted both sides)
            #pragma unroll
            for (int d = 0; d < 4; d++) {
                #pragma unroll
                for (int c = 0; c < 2; c++) {
                    const short8 vf = *(const short8*)&Vs[d * 16 + l16][((c * 4 + quad) ^ swz) * 8];
                    o_acc[mi][d] = __builtin_amdgcn_mfma_f32_16x16x32_bf16(pf[c], vf, o_acc[mi][d], 0, 0, 0);
                }
            }
        }
    }

    // ---- out[b, qi, h*64 + dh] = o / l
    #pragma unroll
    for (int mi = 0; mi < 2; mi++)
        #pragma unroll
        for (int r = 0; r < 4; r++) {
            const float inv = 1.0f / l_run[mi][r];
            const int qi = q0 + wave * 32 + mi * 16 + quad * 4 + r;
            #pragma unroll
            for (int d = 0; d < 4; d++)
                out[(size_t)(b * S_LEN + qi) * D_MODEL + h * DH + d * 16 + l16] =
                    f2bf(o_acc[mi][d][r] * inv);
        }
}

// ---------------------------------------------------------------------------
extern "C" void kernel_launch(void* const* d_in, const int* in_sizes, int n_in,
                              void* d_out, int out_size, void* d_ws, size_t ws_size,
                              hipStream_t stream)
{
    const float* x    = (const float*)d_in[0];
    const float* Wqkv = (const float*)d_in[1];
    const float* bqkv = (const float*)d_in[2];
    const float* Wo   = (const float*)d_in[3];
    const float* bo   = (const float*)d_in[4];
    float* out = (float*)d_out;

    ushort_t* xb    = (ushort_t*)d_ws;                       // N0
    ushort_t* wqkvb = xb + N0;                               // N1
    ushort_t* wob   = wqkvb + N1;                            // N2
    ushort_t* qkbuf = wob + N2;                              // 8192*2048
    ushort_t* vtbuf = qkbuf + (size_t)M_ROWS * 2048;         // B*NH*DH*S
    ushort_t* att   = vtbuf + (size_t)BATCH * NH * DH * S_LEN; // 8192*1024
    // total = 92.3 MB

    dim3 blk(256);
    cvt_f32_bf16<<<dim3((NQUADS + 255) / 256), blk, 0, stream>>>(x, Wqkv, Wo, xb, wqkvb, wob);
    // QKV projection: M=8192, N=3072, K=1024 -> qk (packed Q|K) + vt (V^T, permuted)
    gemm_bt_bias<false, true><<<dim3((3 * D_MODEL) / 128, M_ROWS / 128), blk, 0, stream>>>(
        xb, wqkvb, bqkv, qkbuf, vtbuf, M_ROWS, 3 * D_MODEL, D_MODEL);
    // causal attention
    attn_causal<<<dim3(S_LEN / BQ, BATCH * NH), blk, 0, stream>>>(qkbuf, vtbuf, att);
    // output projection: M=8192, N=1024, K=1024 -> fp32 d_out
    gemm_bt_bias<true, false><<<dim3(D_MODEL / 128, M_ROWS / 128), blk, 0, stream>>>(
        att, wob, bo, out, nullptr, M_ROWS, D_MODEL, D_MODEL);
}

// Round 10
// 281.367 us; speedup vs baseline: 2.0458x; 1.2197x over previous
//
#include <hip/hip_runtime.h>

#define D_MODEL 1024
#define S_LEN   2048
#define BATCH   4
#define NH      16
#define DH      64
#define M_ROWS  (BATCH * S_LEN)   // 8192

typedef __attribute__((ext_vector_type(8))) short short8;
typedef __attribute__((ext_vector_type(4))) float floatx4;
typedef unsigned short ushort_t;
typedef __attribute__((ext_vector_type(4))) ushort_t ushortx4;

__device__ __forceinline__ ushort_t f2bf(float f) {
    union { float f; unsigned u; } v; v.f = f;
    unsigned r = v.u + 0x7FFFu + ((v.u >> 16) & 1u);
    return (ushort_t)(r >> 16);
}

// pack two f32 -> two bf16 (truncating) in one v_perm: low = lo, high = hi
__device__ __forceinline__ int pack2(float lo, float hi) {
    return (int)__builtin_amdgcn_perm(__float_as_uint(hi), __float_as_uint(lo), 0x07060302u);
}

// max over the 16 lanes of a DPP row via row_ror — no LDS round-trip
__device__ __forceinline__ float rowmax16(float x) {
    float t;
    t = __int_as_float(__builtin_amdgcn_update_dpp(0, __float_as_int(x), 0x121, 0xf, 0xf, true)); x = fmaxf(x, t);
    t = __int_as_float(__builtin_amdgcn_update_dpp(0, __float_as_int(x), 0x122, 0xf, 0xf, true)); x = fmaxf(x, t);
    t = __int_as_float(__builtin_amdgcn_update_dpp(0, __float_as_int(x), 0x124, 0xf, 0xf, true)); x = fmaxf(x, t);
    t = __int_as_float(__builtin_amdgcn_update_dpp(0, __float_as_int(x), 0x128, 0xf, 0xf, true)); x = fmaxf(x, t);
    return x;
}

// async global->LDS, 16B/lane; LDS dest = wave-uniform base + lane*16
__device__ __forceinline__ void async_copy16(const ushort_t* g, ushort_t* l) {
    __builtin_amdgcn_global_load_lds(
        (const __attribute__((address_space(1))) void*)g,
        (__attribute__((address_space(3))) void*)l,
        16, 0, 0);
}

// ---------------------------------------------------------------------------
// fp32 -> bf16 downcast of x, W_qkv, W_o into workspace. 4 elems / thread.
// ---------------------------------------------------------------------------
#define N0 (M_ROWS * D_MODEL)        // x:      8,388,608
#define N1 (3 * D_MODEL * D_MODEL)   // W_qkv:  3,145,728
#define N2 (D_MODEL * D_MODEL)       // W_o:    1,048,576
#define NQUADS ((N0 + N1 + N2) / 4)

__global__ __launch_bounds__(256)
void cvt_f32_bf16(const float* __restrict__ s0, const float* __restrict__ s1,
                  const float* __restrict__ s2, ushort_t* __restrict__ d0,
                  ushort_t* __restrict__ d1, ushort_t* __restrict__ d2)
{
    const int q = blockIdx.x * 256 + threadIdx.x;
    if (q >= NQUADS) return;
    const float* s; ushort_t* d; int e;
    if (q < N0 / 4)            { s = s0; d = d0; e = q * 4; }
    else if (q < (N0 + N1) / 4){ s = s1; d = d1; e = q * 4 - N0; }
    else                       { s = s2; d = d2; e = q * 4 - N0 - N1; }
    const float4 v = *(const float4*)&s[e];
    ushortx4 o;
    o[0] = f2bf(v.x); o[1] = f2bf(v.y); o[2] = f2bf(v.z); o[3] = f2bf(v.w);
    *(ushortx4*)&d[e] = o;
}

// ---------------------------------------------------------------------------
// NT GEMM: C[M,N] = A[M,K] * B[N,K]^T + bias[N]. bf16 in, fp32 acc.
// BK=64, DMA staging (global_load_lds w16), XOR-swizzled unpadded LDS tiles.
// VSPLIT (QKV): cols [0,2048) -> qk; cols [2048,3072) -> vt[b][h][dh][sperm],
// sperm = per-64-tile pos(k)=(k&15)*4+(k>>4) (matches attention fragments).
// ---------------------------------------------------------------------------
template<bool F32OUT, bool VSPLIT>
__global__ __launch_bounds__(256)
void gemm_bt_bias(const ushort_t* __restrict__ A, const ushort_t* __restrict__ B,
                  const float* __restrict__ bias, void* __restrict__ Cv,
                  ushort_t* __restrict__ vt, int M, int N, int K)
{
    constexpr int BK = 64;
    __shared__ ushort_t As[128][BK];
    __shared__ ushort_t Bs[128][BK];

    const int tid  = threadIdx.x;
    const int lane = tid & 63;
    const int wave = tid >> 6;
    const int quad = lane >> 4;
    const int l16  = lane & 15;
    const int bm   = blockIdx.y * 128;
    const int bn   = blockIdx.x * 128;
    const int wm   = (wave & 1) * 64;
    const int wn   = (wave >> 1) * 64;

    floatx4 acc[4][4] = {};

    const int l8r = lane >> 3;
    const int c8  = lane & 7;
    const int swz = l16 & 7;

    for (int k0 = 0; k0 < K; k0 += BK) {
        __syncthreads();
        #pragma unroll
        for (int i = wave; i < 16; i += 4) {
            const int row = i * 8 + l8r;
            const int cc  = (c8 ^ l8r) * 8;
            async_copy16(&A[(size_t)(bm + row) * K + k0 + cc], &As[i * 8][0]);
            async_copy16(&B[(size_t)(bn + row) * K + k0 + cc], &Bs[i * 8][0]);
        }
        __syncthreads();

        #pragma unroll
        for (int h = 0; h < 2; h++) {
            short8 af[4], bfr[4];
            #pragma unroll
            for (int i = 0; i < 4; i++)
                af[i]  = *(const short8*)&As[wm + i * 16 + l16][((h * 4 + quad) ^ swz) * 8];
            #pragma unroll
            for (int i = 0; i < 4; i++)
                bfr[i] = *(const short8*)&Bs[wn + i * 16 + l16][((h * 4 + quad) ^ swz) * 8];

            #pragma unroll
            for (int mi = 0; mi < 4; mi++)
                #pragma unroll
                for (int ni = 0; ni < 4; ni++)
                    acc[mi][ni] = __builtin_amdgcn_mfma_f32_16x16x32_bf16(af[mi], bfr[ni], acc[mi][ni], 0, 0, 0);
        }
    }

    #pragma unroll
    for (int ni = 0; ni < 4; ni++) {
        const int col = bn + wn + ni * 16 + l16;
        const float bv = bias[col];
        #pragma unroll
        for (int mi = 0; mi < 4; mi++)
            #pragma unroll
            for (int r = 0; r < 4; r++) {
                const int row = bm + wm + mi * 16 + quad * 4 + r;
                const float val = acc[mi][ni][r] + bv;
                if (VSPLIT) {
                    if (col < 2 * D_MODEL) {
                        ((ushort_t*)Cv)[(size_t)row * 2048 + col] = f2bf(val);
                    } else {
                        const int vcol = col - 2 * D_MODEL;
                        const int h = vcol >> 6, dh = vcol & 63;
                        const int b = row >> 11, s = row & 2047;
                        const int sp = (s & ~63) | ((s & 15) << 2) | ((s >> 4) & 3);
                        vt[(((size_t)(b * NH + h)) * DH + dh) * S_LEN + sp] = f2bf(val);
                    }
                } else if (F32OUT) {
                    ((float*)Cv)[(size_t)row * N + col] = val;
                } else {
                    ((ushort_t*)Cv)[(size_t)row * N + col] = f2bf(val);
                }
            }
    }
}

// ---------------------------------------------------------------------------
// Causal flash attention with UNIFORM-WORK PAIRING.
// Block (p, bh) handles q-tiles qa=p and qb=31-p (64 rows each, 4 waves x 16).
// Key loop kb=0..qb stages each K/V tile ONCE (qa's range is a subset) and
// applies it to both q-tiles -> exactly 33 compute-tiles per block (balanced;
// R9's 2..32-tile skew caused the 21%-occupancy drain tail).
// Swizzled DMA staging (conflicts=0, R8), DPP row-max, exp2 softmax, v_perm
// P-pack, MFMA row-sums, per-64-tile permuted V.
// ---------------------------------------------------------------------------
#define BKV 64

struct TileState {
    short8  qf[2];
    floatx4 o[4];
    float   m[4];
    float   l[4];
};

__device__ __forceinline__ void attn_tile(
    const ushort_t (*__restrict__ Ks)[DH], const ushort_t (*__restrict__ Vs)[BKV],
    ushort_t (*__restrict__ Psw)[BKV + 4], TileState& st, bool diag,
    int wave, int quad, int l16, int swz, short8 ones)
{
    const float C2 = 0.18033688011112042f;   // 0.125 * log2(e)

    // ---- S = Q K^T (swizzled, conflict-free)
    floatx4 sc[4];
    #pragma unroll
    for (int ns = 0; ns < 4; ns++) {
        const short8 kf0 = *(const short8*)&Ks[ns * 16 + l16][(quad ^ swz) * 8];
        const short8 kf1 = *(const short8*)&Ks[ns * 16 + l16][((4 + quad) ^ swz) * 8];
        floatx4 z = {};
        z = __builtin_amdgcn_mfma_f32_16x16x32_bf16(st.qf[0], kf0, z, 0, 0, 0);
        z = __builtin_amdgcn_mfma_f32_16x16x32_bf16(st.qf[1], kf1, z, 0, 0, 0);
        sc[ns] = z;
    }

    // ---- exp2-domain scale + causal mask (diag only) + DPP row max
    float mt[4];
    #pragma unroll
    for (int r = 0; r < 4; r++) {
        const int qloc = wave * 16 + quad * 4 + r;   // row within the 64-row q-tile
        float mx = -1e30f;
        #pragma unroll
        for (int ns = 0; ns < 4; ns++) {
            float v = sc[ns][r] * C2;
            if (diag) {
                const int kj = ns * 16 + l16;
                v = (kj <= qloc) ? v : -1e30f;
            }
            sc[ns][r] = v;
            mx = fmaxf(mx, v);
        }
        mt[r] = rowmax16(mx);
    }

    // ---- online update + exp2 + pack + one b64 write per row
    float alpha[4];
    #pragma unroll
    for (int r = 0; r < 4; r++) {
        const float mnew = fmaxf(st.m[r], mt[r]);
        alpha[r] = __builtin_amdgcn_exp2f(st.m[r] - mnew);
        st.m[r] = mnew;
        const float p0 = __builtin_amdgcn_exp2f(sc[0][r] - mnew);
        const float p1 = __builtin_amdgcn_exp2f(sc[1][r] - mnew);
        const float p2 = __builtin_amdgcn_exp2f(sc[2][r] - mnew);
        const float p3 = __builtin_amdgcn_exp2f(sc[3][r] - mnew);
        int2 w;
        w.x = pack2(p0, p1);
        w.y = pack2(p2, p3);
        *(int2*)&Psw[quad * 4 + r][l16 * 4] = w;
    }

    // ---- P A-fragments (same-wave RAW through LDS)
    short8 pf[2];
    #pragma unroll
    for (int c = 0; c < 2; c++)
        pf[c] = *(const short8*)&Psw[l16][c * 32 + quad * 8];

    // ---- row sums via MFMA
    floatx4 racc = {};
    racc = __builtin_amdgcn_mfma_f32_16x16x32_bf16(pf[0], ones, racc, 0, 0, 0);
    racc = __builtin_amdgcn_mfma_f32_16x16x32_bf16(pf[1], ones, racc, 0, 0, 0);

    #pragma unroll
    for (int r = 0; r < 4; r++)
        st.l[r] = st.l[r] * alpha[r] + racc[r];

    #pragma unroll
    for (int d = 0; d < 4; d++)
        #pragma unroll
        for (int r = 0; r < 4; r++)
            st.o[d][r] *= alpha[r];

    // ---- O += P V (swizzled, position-permuted both sides)
    #pragma unroll
    for (int d = 0; d < 4; d++) {
        #pragma unroll
        for (int c = 0; c < 2; c++) {
            const short8 vf = *(const short8*)&Vs[d * 16 + l16][((c * 4 + quad) ^ swz) * 8];
            st.o[d] = __builtin_amdgcn_mfma_f32_16x16x32_bf16(pf[c], vf, st.o[d], 0, 0, 0);
        }
    }
}

__global__ __launch_bounds__(256, 4)
void attn_causal(const ushort_t* __restrict__ qk, const ushort_t* __restrict__ vt,
                 ushort_t* __restrict__ out)
{
    __shared__ ushort_t Ks[BKV][DH];          // swizzled (8 KB)
    __shared__ ushort_t Vs[DH][BKV];          // swizzled (8 KB)
    __shared__ ushort_t Ps[4][16][BKV + 4];   // per-wave (8.5 KB)

    const int tid  = threadIdx.x;
    const int lane = tid & 63;
    const int wave = tid >> 6;
    const int quad = lane >> 4;
    const int l16  = lane & 15;
    const int l8r  = lane >> 3;
    const int c8   = lane & 7;
    const int swz  = l16 & 7;

    const int qa = blockIdx.x;          // 0..15
    const int qb = 31 - qa;             // 16..31
    const int bh = blockIdx.y;
    const int b  = bh >> 4;
    const int h  = bh & 15;

    const size_t qkbase = (size_t)b * S_LEN * 2048;
    const ushort_t* kg = qk + qkbase + D_MODEL + h * DH;
    const ushort_t* vg = vt + (size_t)(b * NH + h) * DH * S_LEN;

    TileState sa, sb;
    #pragma unroll
    for (int r = 0; r < 4; r++) { sa.m[r] = -1e30f; sa.l[r] = 0.f; sb.m[r] = -1e30f; sb.l[r] = 0.f; }
    #pragma unroll
    for (int d = 0; d < 4; d++) { sa.o[d] = (floatx4){}; sb.o[d] = (floatx4){}; }

    {
        const ushort_t* qpa = qk + qkbase + (size_t)(qa * 64 + wave * 16 + l16) * 2048 + h * DH;
        sa.qf[0] = *(const short8*)(qpa + quad * 8);
        sa.qf[1] = *(const short8*)(qpa + 32 + quad * 8);
        const ushort_t* qpb = qk + qkbase + (size_t)(qb * 64 + wave * 16 + l16) * 2048 + h * DH;
        sb.qf[0] = *(const short8*)(qpb + quad * 8);
        sb.qf[1] = *(const short8*)(qpb + 32 + quad * 8);
    }

    short8 ones;
    #pragma unroll
    for (int j = 0; j < 8; j++) ones[j] = (short)0x3F80;   // bf16 1.0

    for (int t = 0; t <= qb; t++) {
        const int kb = t * BKV;
        __syncthreads();
        #pragma unroll
        for (int i = wave; i < 8; i += 4) {
            const int row = i * 8 + l8r;
            const int cc  = (c8 ^ l8r) * 8;
            async_copy16(&kg[(size_t)(kb + row) * 2048 + cc], &Ks[i * 8][0]);
            async_copy16(&vg[(size_t)row * S_LEN + kb + cc], &Vs[i * 8][0]);
        }
        __syncthreads();

        if (t <= qa) attn_tile(Ks, Vs, Ps[wave], sa, t == qa, wave, quad, l16, swz, ones);
        attn_tile(Ks, Vs, Ps[wave], sb, t == qb, wave, quad, l16, swz, ones);
    }

    // ---- epilogue: out[b, qi, h*64 + dh] = o / l  (both tiles)
    #pragma unroll
    for (int r = 0; r < 4; r++) {
        const float inva = 1.0f / sa.l[r];
        const float invb = 1.0f / sb.l[r];
        const int ra = qa * 64 + wave * 16 + quad * 4 + r;
        const int rb = qb * 64 + wave * 16 + quad * 4 + r;
        #pragma unroll
        for (int d = 0; d < 4; d++) {
            out[(size_t)(b * S_LEN + ra) * D_MODEL + h * DH + d * 16 + l16] = f2bf(sa.o[d][r] * inva);
            out[(size_t)(b * S_LEN + rb) * D_MODEL + h * DH + d * 16 + l16] = f2bf(sb.o[d][r] * invb);
        }
    }
}

// ---------------------------------------------------------------------------
extern "C" void kernel_launch(void* const* d_in, const int* in_sizes, int n_in,
                              void* d_out, int out_size, void* d_ws, size_t ws_size,
                              hipStream_t stream)
{
    const float* x    = (const float*)d_in[0];
    const float* Wqkv = (const float*)d_in[1];
    const float* bqkv = (const float*)d_in[2];
    const float* Wo   = (const float*)d_in[3];
    const float* bo   = (const float*)d_in[4];
    float* out = (float*)d_out;

    ushort_t* xb    = (ushort_t*)d_ws;                       // N0
    ushort_t* wqkvb = xb + N0;                               // N1
    ushort_t* wob   = wqkvb + N1;                            // N2
    ushort_t* qkbuf = wob + N2;                              // 8192*2048
    ushort_t* vtbuf = qkbuf + (size_t)M_ROWS * 2048;         // B*NH*DH*S
    ushort_t* att   = vtbuf + (size_t)BATCH * NH * DH * S_LEN; // 8192*1024
    // total = 92.3 MB

    dim3 blk(256);
    cvt_f32_bf16<<<dim3((NQUADS + 255) / 256), blk, 0, stream>>>(x, Wqkv, Wo, xb, wqkvb, wob);
    // QKV projection: M=8192, N=3072, K=1024 -> qk (packed Q|K) + vt (V^T, permuted)
    gemm_bt_bias<false, true><<<dim3((3 * D_MODEL) / 128, M_ROWS / 128), blk, 0, stream>>>(
        xb, wqkvb, bqkv, qkbuf, vtbuf, M_ROWS, 3 * D_MODEL, D_MODEL);
    // causal attention (paired q-tiles, uniform work)
    attn_causal<<<dim3(16, BATCH * NH), blk, 0, stream>>>(qkbuf, vtbuf, att);
    // output projection: M=8192, N=1024, K=1024 -> fp32 d_out
    gemm_bt_bias<true, false><<<dim3(D_MODEL / 128, M_ROWS / 128), blk, 0, stream>>>(
        att, wob, bo, out, nullptr, M_ROWS, D_MODEL, D_MODEL);
}